// Round 2
// baseline (920.937 us; speedup 1.0000x reference)
//
#include <hip/hip_runtime.h>
#include <math.h>

#define B_ 8
#define N_ 16384
#define D_ 384
#define TD_ 1152
#define M_ (B_*N_)
#define CTX_ELEMS (B_*8*48*48)    /* 147456 fp32 */
#define Z_ELEMS   (B_*8*48)       /* 3072 fp32   */

typedef __attribute__((ext_vector_type(8))) short short8;
typedef __attribute__((ext_vector_type(4))) float f32x4;
typedef __attribute__((ext_vector_type(4))) unsigned short us4;
typedef __attribute__((ext_vector_type(8))) unsigned short us8;

__device__ __forceinline__ unsigned short f2bf(float f){
    union { float f; unsigned u; } v; v.f = f;
    unsigned r = v.u + 0x7FFFu + ((v.u >> 16) & 1u);   // RNE
    return (unsigned short)(r >> 16);
}

#define MFMA(a,b,c) __builtin_amdgcn_mfma_f32_16x16x32_bf16((a),(b),(c),0,0,0)

// ---------------------------------------------------------------------------
// kP: transpose + bf16-ify weights. WqkvT[col][d] (1152x384), WpT[col][d] (384x384)
// ---------------------------------------------------------------------------
__global__ void kP(const float* __restrict__ Wqkv, const float* __restrict__ Wp,
                   unsigned short* __restrict__ WqkvT, unsigned short* __restrict__ WpT)
{
    __shared__ float t[32][33];
    int bi = blockIdx.x;
    const float* src; unsigned short* dst; int ldS, c0, d0;
    if (bi < 432) { src = Wqkv; dst = WqkvT; ldS = 1152; c0 = (bi % 36) * 32; d0 = (bi / 36) * 32; }
    else { bi -= 432; src = Wp; dst = WpT; ldS = 384; c0 = (bi % 12) * 32; d0 = (bi / 12) * 32; }
    const int cx = threadIdx.x & 31, ry = threadIdx.x >> 5;
#pragma unroll
    for (int k = 0; k < 4; ++k) {
        int r = ry + k * 8;
        t[r][cx] = src[(size_t)(d0 + r) * ldS + c0 + cx];
    }
    __syncthreads();
#pragma unroll
    for (int k = 0; k < 4; ++k) {
        int r = ry + k * 8;
        dst[(size_t)(c0 + r) * 384 + d0 + cx] = f2bf(t[cx][r]);
    }
}

// ---------------------------------------------------------------------------
// kA: per block (512 thr = 8 waves, wave = head): 8 token-tiles of 64.
// T14 software pipeline: stage-write(g) | barrier | issue-loads(g+1) |
// k,v GEMM | exp->kv | barrier | ctx MFMA.  Loads for g+1 fly under the
// ~2500-cycle compute phase, so per-tile HBM latency is hidden.
// grid = 256 (32 blocks per batch x 8 tiles each).
// ---------------------------------------------------------------------------
__global__ __launch_bounds__(512, 2) void kA(const float* __restrict__ x,
        const unsigned short* __restrict__ WqkvT,
        float* __restrict__ ctx, float* __restrict__ Z)
{
    __shared__ __align__(16) unsigned short xs[64 * 392];    // x tile, [t][d], bf16
    __shared__ __align__(16) unsigned short kv[8 * 96 * 64]; // per-wave [row96][t64], XOR-swizzled

    const int tid = threadIdx.x;
    const int w   = tid >> 6;       // wave = head
    const int l   = tid & 63;
    const int q   = l >> 4;
    const int c16 = l & 15;
    const int blk = blockIdx.x;
    const int b   = blk >> 5;
    const int tbase = (blk & 31) * 8;
    unsigned short* kvw = kv + w * (96 * 64);

    f32x4 ctxacc[3][3];
    float zp[3] = {0.f, 0.f, 0.f};
#pragma unroll
    for (int i = 0; i < 3; ++i)
#pragma unroll
        for (int j = 0; j < 3; ++j) ctxacc[i][j] = (f32x4){0.f, 0.f, 0.f, 0.f};

    const int st = tid >> 3, sq = tid & 7;

    // --- T14 stage registers: tile g's x rows held as fp32 across the loop ---
    float4 r[12];
    {   // prologue: issue loads for tile 0 (latency exposed once per block)
        const float* xg = x + ((size_t)b * 16384 + (size_t)tbase * 64 + st) * 384 + sq * 4;
#pragma unroll
        for (int i = 0; i < 12; ++i) r[i] = *(const float4*)(xg + i * 32);
    }

    for (int g = 0; g < 8; ++g) {
        // [A] convert + write tile g into xs (all waves passed [F](g-1): xs free)
        {
            unsigned short* xw = xs + st * 392 + sq * 4;
#pragma unroll
            for (int i = 0; i < 12; ++i) {
                float4 v = r[i];
                us4 o; o.x = f2bf(v.x); o.y = f2bf(v.y); o.z = f2bf(v.z); o.w = f2bf(v.w);
                *(us4*)(xw + i * 32) = o;
            }
        }
        __syncthreads();   // [B] xs ready for all waves

        // [C] issue next tile's global loads; they stay in flight under [D]+[E]
        if (g + 1 < 8) {
            const float* xg = x + ((size_t)b * 16384 + (size_t)(tbase + g + 1) * 64 + st) * 384 + sq * 4;
#pragma unroll
            for (int i = 0; i < 12; ++i) r[i] = *(const float4*)(xg + i * 32);
        }

        // [D] k,v GEMM: 64 tok x 96 cols (this head's k:48 + v:48), K=384
        f32x4 kva[4][6];
#pragma unroll
        for (int mt = 0; mt < 4; ++mt)
#pragma unroll
            for (int j = 0; j < 6; ++j) kva[mt][j] = (f32x4){0.f, 0.f, 0.f, 0.f};

#pragma unroll
        for (int ks = 0; ks < 12; ++ks) {
            short8 a[4];
#pragma unroll
            for (int mt = 0; mt < 4; ++mt)
                a[mt] = *(const short8*)(xs + (mt * 16 + c16) * 392 + ks * 32 + q * 8);
#pragma unroll
            for (int j = 0; j < 6; ++j) {
                const int colrow = (j < 3) ? (384 + w * 48 + j * 16 + c16)
                                           : (768 + w * 48 + (j - 3) * 16 + c16);
                short8 bf = *(const short8*)(WqkvT + (size_t)colrow * 384 + ks * 32 + q * 8);
#pragma unroll
                for (int mt = 0; mt < 4; ++mt)
                    kva[mt][j] = MFMA(a[mt], bf, kva[mt][j]);
            }
        }

        // [E] exp(k), pack bf16, write swizzled [row][t]
#pragma unroll
        for (int mt = 0; mt < 4; ++mt) {
            const int chunk = 2 * mt + (q >> 1);
            const int tin = (q & 1) * 4;
#pragma unroll
            for (int j = 0; j < 6; ++j) {
                f32x4 vv = kva[mt][j];
                us4 o;
                int row;
                if (j < 3) {
                    row = j * 16 + c16;
                    float e0 = __expf(vv.x), e1 = __expf(vv.y), e2 = __expf(vv.z), e3 = __expf(vv.w);
                    zp[j] += (e0 + e1) + (e2 + e3);
                    o.x = f2bf(e0); o.y = f2bf(e1); o.z = f2bf(e2); o.w = f2bf(e3);
                } else {
                    row = 48 + (j - 3) * 16 + c16;
                    o.x = f2bf(vv.x); o.y = f2bf(vv.y); o.z = f2bf(vv.z); o.w = f2bf(vv.w);
                }
                *(us4*)(kvw + row * 64 + ((chunk ^ (row & 7)) << 3) + tin) = o;
            }
        }
        __syncthreads();   // [F] protects xs ([A] of g+1); kv is wave-private

        // [G] ctx MFMA: ctx[c][d] += ek^T . v over this tile's 64 tokens
#pragma unroll
        for (int kt = 0; kt < 2; ++kt) {
            short8 af[3], bf2[3];
#pragma unroll
            for (int i = 0; i < 3; ++i) {
                const int ra = i * 16 + c16;
                af[i]  = *(const short8*)(kvw + ra * 64 + (((kt * 4 + q) ^ (ra & 7)) << 3));
                const int rb = 48 + i * 16 + c16;
                bf2[i] = *(const short8*)(kvw + rb * 64 + (((kt * 4 + q) ^ (rb & 7)) << 3));
            }
#pragma unroll
            for (int ct = 0; ct < 3; ++ct)
#pragma unroll
                for (int dt = 0; dt < 3; ++dt)
                    ctxacc[ct][dt] = MFMA(af[ct], bf2[dt], ctxacc[ct][dt]);
        }
    }

    // --- finalize: Z and ctx atomics ---
#pragma unroll
    for (int j = 0; j < 3; ++j) {
        float v = zp[j];
        v += __shfl_xor(v, 16);
        v += __shfl_xor(v, 32);
        if (l < 16) atomicAdd(&Z[(b * 8 + w) * 48 + j * 16 + c16], v);
    }
#pragma unroll
    for (int ct = 0; ct < 3; ++ct)
#pragma unroll
        for (int dt = 0; dt < 3; ++dt)
#pragma unroll
            for (int r2 = 0; r2 < 4; ++r2) {
                const int c = ct * 16 + q * 4 + r2;
                const int d = dt * 16 + c16;
                atomicAdd(&ctx[((size_t)(b * 8 + w) * 48 + c) * 48 + d], ctxacc[ct][dt][r2]);
            }
}

// ---------------------------------------------------------------------------
// kB: ctxT[bh][d][c(pad 64)] = bf16( ctx[bh][c][d] / Z[bh][c] ), pad zeros.
// ---------------------------------------------------------------------------
__global__ void kB(const float* __restrict__ ctx, const float* __restrict__ Z,
                   unsigned short* __restrict__ ctxT)
{
    const int e = blockIdx.x * 256 + threadIdx.x;    // < 196608
    const int bh = e / 3072;
    const int r = e % 3072;
    const int d = r >> 6;
    const int c = r & 63;
    float v = 0.f;
    if (c < 48) v = ctx[((size_t)bh * 48 + c) * 48 + d] / Z[bh * 48 + c];
    ctxT[e] = f2bf(v);
}

// ---------------------------------------------------------------------------
// kC: per 32-token block (256 thr = 4 waves, wave = 2 heads):
// q-GEMM (MFMA) -> in-register softmax (shfl) -> y = q̂@ctx (MFMA) -> proj (MFMA)+bias.
// grid = 4096.
// ---------------------------------------------------------------------------
__global__ __launch_bounds__(256, 2) void kC(const float* __restrict__ x,
        const unsigned short* __restrict__ WqkvT,
        const unsigned short* __restrict__ ctxT,
        const unsigned short* __restrict__ WpT,
        const float* __restrict__ bp, float* __restrict__ out)
{
    __shared__ __align__(16) unsigned short xs[32 * 392];   // x tile; reused as y tile
    __shared__ __align__(16) unsigned short qs[32 * 520];   // q̂ in A-layout [t][h*64+c]

    const int tid = threadIdx.x;
    const int w   = tid >> 6;
    const int l   = tid & 63;
    const int q   = l >> 4;
    const int c16 = l & 15;
    const int blk = blockIdx.x;
    const size_t tok0 = (size_t)blk * 32;
    const int b = blk >> 9;

    {   // stage x
        const int st = tid >> 3, sq = tid & 7;
        const float* xg = x + (tok0 + st) * 384 + sq * 4;
        unsigned short* xw = xs + st * 392 + sq * 4;
#pragma unroll
        for (int i = 0; i < 12; ++i) {
            float4 v = *(const float4*)(xg + i * 32);
            us4 o; o.x = f2bf(v.x); o.y = f2bf(v.y); o.z = f2bf(v.z); o.w = f2bf(v.w);
            *(us4*)(xw + i * 32) = o;
        }
    }
    __syncthreads();

    // --- q-GEMM: 32 tok x 96 cols per wave (heads 2w, 2w+1), K=384 ---
    f32x4 acc[2][6];
#pragma unroll
    for (int mt = 0; mt < 2; ++mt)
#pragma unroll
        for (int j = 0; j < 6; ++j) acc[mt][j] = (f32x4){0.f, 0.f, 0.f, 0.f};

#pragma unroll
    for (int ks = 0; ks < 12; ++ks) {
        short8 a0 = *(const short8*)(xs + (c16) * 392 + ks * 32 + q * 8);
        short8 a1 = *(const short8*)(xs + (16 + c16) * 392 + ks * 32 + q * 8);
#pragma unroll
        for (int j = 0; j < 6; ++j) {
            const int nt = w * 6 + j;
            short8 bf = *(const short8*)(WqkvT + (size_t)(nt * 16 + c16) * 384 + ks * 32 + q * 8);
            acc[0][j] = MFMA(a0, bf, acc[0][j]);
            acc[1][j] = MFMA(a1, bf, acc[1][j]);
        }
    }
    __syncthreads();    // xs free for reuse as ys

    // --- softmax over C=48 per (token, head), fully in registers + shfl ---
#pragma unroll
    for (int hh = 0; hh < 2; ++hh) {
        const int h = 2 * w + hh;
        f32x4 e[2][3];
#pragma unroll
        for (int mt = 0; mt < 2; ++mt)
#pragma unroll
            for (int jj = 0; jj < 3; ++jj) {
                f32x4 vv = acc[mt][hh * 3 + jj];
                e[mt][jj].x = __expf(vv.x); e[mt][jj].y = __expf(vv.y);
                e[mt][jj].z = __expf(vv.z); e[mt][jj].w = __expf(vv.w);
            }
#pragma unroll
        for (int mt = 0; mt < 2; ++mt)
#pragma unroll
            for (int r = 0; r < 4; ++r) {
                float s = e[mt][0][r] + e[mt][1][r] + e[mt][2][r];
                s += __shfl_xor(s, 1); s += __shfl_xor(s, 2);
                s += __shfl_xor(s, 4); s += __shfl_xor(s, 8);
                const float inv = 1.0f / s;
                e[mt][0][r] *= inv; e[mt][1][r] *= inv; e[mt][2][r] *= inv;
            }
        // write q̂ (A-layout, column writes)
#pragma unroll
        for (int mt = 0; mt < 2; ++mt)
#pragma unroll
            for (int jj = 0; jj < 3; ++jj) {
                const int c = jj * 16 + c16;
#pragma unroll
                for (int r = 0; r < 4; ++r) {
                    const int t = mt * 16 + q * 4 + r;
                    qs[t * 520 + h * 64 + c] = f2bf(e[mt][jj][r]);
                }
            }
    }
    {   // zero the K-pad region c in [48,64) for this wave's heads
        const int t = l & 31, hp = l >> 5;
        const int h = 2 * w + hp;
        us8 z8 = {0, 0, 0, 0, 0, 0, 0, 0};
        *(us8*)(qs + t * 520 + h * 64 + 48) = z8;
    }
    __syncthreads();

    // --- y = q̂ @ ctx̂ per head (K=64 padded), write y bf16 into xs as [t][384] ---
#pragma unroll
    for (int hh = 0; hh < 2; ++hh) {
        const int h = 2 * w + hh;
        f32x4 y[2][3];
#pragma unroll
        for (int mt = 0; mt < 2; ++mt)
#pragma unroll
            for (int dt = 0; dt < 3; ++dt) y[mt][dt] = (f32x4){0.f, 0.f, 0.f, 0.f};
#pragma unroll
        for (int ks = 0; ks < 2; ++ks) {
            short8 a0 = *(const short8*)(qs + (c16) * 520 + h * 64 + ks * 32 + q * 8);
            short8 a1 = *(const short8*)(qs + (16 + c16) * 520 + h * 64 + ks * 32 + q * 8);
#pragma unroll
            for (int dt = 0; dt < 3; ++dt) {
                short8 bf = *(const short8*)(ctxT + ((size_t)(b * 8 + h) * 48 + dt * 16 + c16) * 64 + ks * 32 + q * 8);
                y[0][dt] = MFMA(a0, bf, y[0][dt]);
                y[1][dt] = MFMA(a1, bf, y[1][dt]);
            }
        }
#pragma unroll
        for (int mt = 0; mt < 2; ++mt)
#pragma unroll
            for (int dt = 0; dt < 3; ++dt) {
                const int dcol = h * 48 + dt * 16 + c16;
#pragma unroll
                for (int r = 0; r < 4; ++r) {
                    const int t = mt * 16 + q * 4 + r;
                    xs[t * 392 + dcol] = f2bf(y[mt][dt][r]);
                }
            }
    }
    __syncthreads();

    // --- proj: out = y @ Wp + b, 32 tok x 96 cols per wave, K=384 ---
    f32x4 po[2][6];
#pragma unroll
    for (int mt = 0; mt < 2; ++mt)
#pragma unroll
        for (int j = 0; j < 6; ++j) po[mt][j] = (f32x4){0.f, 0.f, 0.f, 0.f};

#pragma unroll
    for (int ks = 0; ks < 12; ++ks) {
        short8 a0 = *(const short8*)(xs + (c16) * 392 + ks * 32 + q * 8);
        short8 a1 = *(const short8*)(xs + (16 + c16) * 392 + ks * 32 + q * 8);
#pragma unroll
        for (int j = 0; j < 6; ++j) {
            const int nt = w * 6 + j;
            short8 bf = *(const short8*)(WpT + (size_t)(nt * 16 + c16) * 384 + ks * 32 + q * 8);
            po[0][j] = MFMA(a0, bf, po[0][j]);
            po[1][j] = MFMA(a1, bf, po[1][j]);
        }
    }

    // --- epilogue: bias + store ---
#pragma unroll
    for (int j = 0; j < 6; ++j) {
        const int col = (w * 6 + j) * 16 + c16;
        const float bv = bp[col];
#pragma unroll
        for (int mt = 0; mt < 2; ++mt)
#pragma unroll
            for (int r = 0; r < 4; ++r) {
                const int t = mt * 16 + q * 4 + r;
                out[(tok0 + t) * 384 + col] = po[mt][j][r] + bv;
            }
    }
}

// ---------------------------------------------------------------------------
extern "C" void kernel_launch(void* const* d_in, const int* in_sizes, int n_in,
                              void* d_out, int out_size, void* d_ws, size_t ws_size,
                              hipStream_t stream)
{
    (void)in_sizes; (void)n_in; (void)out_size; (void)ws_size;
    const float* x    = (const float*)d_in[0];
    const float* Wqkv = (const float*)d_in[1];
    const float* Wp   = (const float*)d_in[2];
    const float* bp   = (const float*)d_in[3];
    float* out = (float*)d_out;

    char* p = (char*)d_ws;
    float* ctx = (float*)p;                 p += CTX_ELEMS * 4;     // 589824 B
    float* Z   = (float*)p;                 p += Z_ELEMS * 4;       // 12288 B
    unsigned short* WqkvT = (unsigned short*)p;  p += TD_ * D_ * 2;      // 884736 B
    unsigned short* WpT   = (unsigned short*)p;  p += D_ * D_ * 2;       // 294912 B
    unsigned short* ctxT  = (unsigned short*)p;                          // 393216 B

    hipMemsetAsync(d_ws, 0, (CTX_ELEMS + Z_ELEMS) * sizeof(float), stream);
    kP<<<dim3(576), dim3(256), 0, stream>>>(Wqkv, Wp, WqkvT, WpT);
    kA<<<dim3(256), dim3(512), 0, stream>>>(x, WqkvT, ctx, Z);
    kB<<<dim3(768), dim3(256), 0, stream>>>(ctx, Z, ctxT);
    kC<<<dim3(4096), dim3(256), 0, stream>>>(x, WqkvT, ctxT, WpT, bp, out);
}

// Round 3
// 845.530 us; speedup vs baseline: 1.0892x; 1.0892x over previous
//
#include <hip/hip_runtime.h>
#include <math.h>

#define B_ 8
#define N_ 16384
#define D_ 384
#define TD_ 1152
#define M_ (B_*N_)
#define CTXP_ELEMS (B_*8*32*48*48)  /* 4718592 fp32: [bh][s][d][c] partials */
#define ZP_ELEMS   (B_*8*32*48)     /* 98304 fp32:   [bh][s][c] partials   */

typedef __attribute__((ext_vector_type(8))) short short8;
typedef __attribute__((ext_vector_type(4))) float f32x4;
typedef __attribute__((ext_vector_type(4))) unsigned short us4;
typedef __attribute__((ext_vector_type(8))) unsigned short us8;

__device__ __forceinline__ unsigned short f2bf(float f){
    union { float f; unsigned u; } v; v.f = f;
    unsigned r = v.u + 0x7FFFu + ((v.u >> 16) & 1u);   // RNE
    return (unsigned short)(r >> 16);
}

#define MFMA(a,b,c) __builtin_amdgcn_mfma_f32_16x16x32_bf16((a),(b),(c),0,0,0)

// ---------------------------------------------------------------------------
// kP: transpose + bf16-ify weights. WqkvT[col][d] (1152x384), WpT[col][d] (384x384)
// ---------------------------------------------------------------------------
__global__ void kP(const float* __restrict__ Wqkv, const float* __restrict__ Wp,
                   unsigned short* __restrict__ WqkvT, unsigned short* __restrict__ WpT)
{
    __shared__ float t[32][33];
    int bi = blockIdx.x;
    const float* src; unsigned short* dst; int ldS, c0, d0;
    if (bi < 432) { src = Wqkv; dst = WqkvT; ldS = 1152; c0 = (bi % 36) * 32; d0 = (bi / 36) * 32; }
    else { bi -= 432; src = Wp; dst = WpT; ldS = 384; c0 = (bi % 12) * 32; d0 = (bi / 12) * 32; }
    const int cx = threadIdx.x & 31, ry = threadIdx.x >> 5;
#pragma unroll
    for (int k = 0; k < 4; ++k) {
        int r = ry + k * 8;
        t[r][cx] = src[(size_t)(d0 + r) * ldS + c0 + cx];
    }
    __syncthreads();
#pragma unroll
    for (int k = 0; k < 4; ++k) {
        int r = ry + k * 8;
        dst[(size_t)(c0 + r) * 384 + d0 + cx] = f2bf(t[cx][r]);
    }
}

// ---------------------------------------------------------------------------
// kA: per block (512 thr = 8 waves, wave = head): 8 token-tiles of 64.
// T14 pipeline; x loads NON-TEMPORAL (zero reuse -> don't evict WqkvT from L2).
// ctx/Z written as per-slice partials (plain nt stores) -> no atomics, no memset.
// grid = 256 (32 slices per batch x 8 tiles each).
// ---------------------------------------------------------------------------
__global__ __launch_bounds__(512, 2) void kA(const float* __restrict__ x,
        const unsigned short* __restrict__ WqkvT,
        float* __restrict__ ctxP, float* __restrict__ ZP)
{
    __shared__ __align__(16) unsigned short xs[64 * 392];    // x tile, [t][d], bf16
    __shared__ __align__(16) unsigned short kv[8 * 96 * 64]; // per-wave [row96][t64], XOR-swizzled

    const int tid = threadIdx.x;
    const int w   = tid >> 6;       // wave = head
    const int l   = tid & 63;
    const int q   = l >> 4;
    const int c16 = l & 15;
    const int blk = blockIdx.x;
    const int b   = blk >> 5;
    const int s   = blk & 31;       // token-slice id (partial index)
    const int tbase = s * 8;
    unsigned short* kvw = kv + w * (96 * 64);

    f32x4 ctxacc[3][3];
    float zp[3] = {0.f, 0.f, 0.f};
#pragma unroll
    for (int i = 0; i < 3; ++i)
#pragma unroll
        for (int j = 0; j < 3; ++j) ctxacc[i][j] = (f32x4){0.f, 0.f, 0.f, 0.f};

    const int st = tid >> 3, sq = tid & 7;

    // --- T14 stage registers: tile g's x rows held as fp32 across the loop ---
    f32x4 r[12];
    {   // prologue: issue loads for tile 0 (latency exposed once per block)
        const float* xg = x + ((size_t)b * 16384 + (size_t)tbase * 64 + st) * 384 + sq * 4;
#pragma unroll
        for (int i = 0; i < 12; ++i)
            r[i] = __builtin_nontemporal_load((const f32x4*)(xg + i * 32));
    }

    for (int g = 0; g < 8; ++g) {
        // [A] convert + write tile g into xs (all waves passed [F](g-1): xs free)
        {
            unsigned short* xw = xs + st * 392 + sq * 4;
#pragma unroll
            for (int i = 0; i < 12; ++i) {
                f32x4 v = r[i];
                us4 o; o.x = f2bf(v.x); o.y = f2bf(v.y); o.z = f2bf(v.z); o.w = f2bf(v.w);
                *(us4*)(xw + i * 32) = o;
            }
        }
        __syncthreads();   // [B] xs ready for all waves

        // [C] issue next tile's global loads; they stay in flight under [D]+[E]
        if (g + 1 < 8) {
            const float* xg = x + ((size_t)b * 16384 + (size_t)(tbase + g + 1) * 64 + st) * 384 + sq * 4;
#pragma unroll
            for (int i = 0; i < 12; ++i)
                r[i] = __builtin_nontemporal_load((const f32x4*)(xg + i * 32));
        }

        // [D] k,v GEMM: 64 tok x 96 cols (this head's k:48 + v:48), K=384
        f32x4 kva[4][6];
#pragma unroll
        for (int mt = 0; mt < 4; ++mt)
#pragma unroll
            for (int j = 0; j < 6; ++j) kva[mt][j] = (f32x4){0.f, 0.f, 0.f, 0.f};

#pragma unroll
        for (int ks = 0; ks < 12; ++ks) {
            short8 a[4];
#pragma unroll
            for (int mt = 0; mt < 4; ++mt)
                a[mt] = *(const short8*)(xs + (mt * 16 + c16) * 392 + ks * 32 + q * 8);
#pragma unroll
            for (int j = 0; j < 6; ++j) {
                const int colrow = (j < 3) ? (384 + w * 48 + j * 16 + c16)
                                           : (768 + w * 48 + (j - 3) * 16 + c16);
                short8 bf = *(const short8*)(WqkvT + (size_t)colrow * 384 + ks * 32 + q * 8);
#pragma unroll
                for (int mt = 0; mt < 4; ++mt)
                    kva[mt][j] = MFMA(a[mt], bf, kva[mt][j]);
            }
        }

        // [E] exp(k), pack bf16, write swizzled [row][t]
#pragma unroll
        for (int mt = 0; mt < 4; ++mt) {
            const int chunk = 2 * mt + (q >> 1);
            const int tin = (q & 1) * 4;
#pragma unroll
            for (int j = 0; j < 6; ++j) {
                f32x4 vv = kva[mt][j];
                us4 o;
                int row;
                if (j < 3) {
                    row = j * 16 + c16;
                    float e0 = __expf(vv.x), e1 = __expf(vv.y), e2 = __expf(vv.z), e3 = __expf(vv.w);
                    zp[j] += (e0 + e1) + (e2 + e3);
                    o.x = f2bf(e0); o.y = f2bf(e1); o.z = f2bf(e2); o.w = f2bf(e3);
                } else {
                    row = 48 + (j - 3) * 16 + c16;
                    o.x = f2bf(vv.x); o.y = f2bf(vv.y); o.z = f2bf(vv.z); o.w = f2bf(vv.w);
                }
                *(us4*)(kvw + row * 64 + ((chunk ^ (row & 7)) << 3) + tin) = o;
            }
        }
        __syncthreads();   // [F] protects xs ([A] of g+1); kv is wave-private

        // [G] ctx MFMA: ctx[c][d] += ek^T . v over this tile's 64 tokens
#pragma unroll
        for (int kt = 0; kt < 2; ++kt) {
            short8 af[3], bf2[3];
#pragma unroll
            for (int i = 0; i < 3; ++i) {
                const int ra = i * 16 + c16;
                af[i]  = *(const short8*)(kvw + ra * 64 + (((kt * 4 + q) ^ (ra & 7)) << 3));
                const int rb = 48 + i * 16 + c16;
                bf2[i] = *(const short8*)(kvw + rb * 64 + (((kt * 4 + q) ^ (rb & 7)) << 3));
            }
#pragma unroll
            for (int ct = 0; ct < 3; ++ct)
#pragma unroll
                for (int dt = 0; dt < 3; ++dt)
                    ctxacc[ct][dt] = MFMA(af[ct], bf2[dt], ctxacc[ct][dt]);
        }
    }

    // --- finalize: plain nt stores of partials (no atomics, no contention) ---
#pragma unroll
    for (int j = 0; j < 3; ++j) {
        float v = zp[j];
        v += __shfl_xor(v, 16);
        v += __shfl_xor(v, 32);
        if (l < 16)
            __builtin_nontemporal_store(v,
                &ZP[((size_t)(b * 8 + w) * 32 + s) * 48 + j * 16 + c16]);
    }
#pragma unroll
    for (int ct = 0; ct < 3; ++ct)
#pragma unroll
        for (int dt = 0; dt < 3; ++dt) {
            const int d  = dt * 16 + c16;
            const int c0 = ct * 16 + q * 4;
            float* dst = ctxP + ((((size_t)(b * 8 + w) * 32 + s) * 48 + d) * 48 + c0);
            __builtin_nontemporal_store(ctxacc[ct][dt], (f32x4*)dst);
        }
}

// ---------------------------------------------------------------------------
// kB: reduce 32 partial slices, divide by Z, transpose-pack to bf16.
// ctxT[bh][d][c(pad 64)] = bf16( sum_s ctxP[bh][s][d][c] / sum_s ZP[bh][s][c] )
// Adjacent threads = adjacent c -> coalesced partial reads and ctxT writes.
// ---------------------------------------------------------------------------
__global__ void kB(const float* __restrict__ ctxP, const float* __restrict__ ZP,
                   unsigned short* __restrict__ ctxT)
{
    const int e = blockIdx.x * 256 + threadIdx.x;    // < 196608
    const int bh = e / 3072;
    const int r = e % 3072;
    const int d = r >> 6;
    const int c = r & 63;
    float v = 0.f;
    if (c < 48) {
        float sum = 0.f, zs = 0.f;
#pragma unroll
        for (int s = 0; s < 32; ++s) {
            sum += __builtin_nontemporal_load(
                       ctxP + ((((size_t)bh * 32 + s) * 48 + d) * 48 + c));
            zs  += ZP[((size_t)bh * 32 + s) * 48 + c];
        }
        v = sum / zs;
    }
    ctxT[e] = f2bf(v);
}

// ---------------------------------------------------------------------------
// kC: per 32-token block (256 thr = 4 waves, wave = 2 heads):
// q-GEMM (MFMA) -> in-register softmax (shfl) -> y = q̂@ctx (MFMA) -> proj (MFMA)+bias.
// x loads + out stores NON-TEMPORAL (zero reuse -> keep WqkvT/WpT/ctxT L2-hot).
// grid = 4096.
// ---------------------------------------------------------------------------
__global__ __launch_bounds__(256, 2) void kC(const float* __restrict__ x,
        const unsigned short* __restrict__ WqkvT,
        const unsigned short* __restrict__ ctxT,
        const unsigned short* __restrict__ WpT,
        const float* __restrict__ bp, float* __restrict__ out)
{
    __shared__ __align__(16) unsigned short xs[32 * 392];   // x tile; reused as y tile
    __shared__ __align__(16) unsigned short qs[32 * 520];   // q̂ in A-layout [t][h*64+c]

    const int tid = threadIdx.x;
    const int w   = tid >> 6;
    const int l   = tid & 63;
    const int q   = l >> 4;
    const int c16 = l & 15;
    const int blk = blockIdx.x;
    const size_t tok0 = (size_t)blk * 32;
    const int b = blk >> 9;

    {   // stage x (non-temporal: each token row is block-exclusive)
        const int st = tid >> 3, sq = tid & 7;
        const float* xg = x + (tok0 + st) * 384 + sq * 4;
        unsigned short* xw = xs + st * 392 + sq * 4;
#pragma unroll
        for (int i = 0; i < 12; ++i) {
            f32x4 v = __builtin_nontemporal_load((const f32x4*)(xg + i * 32));
            us4 o; o.x = f2bf(v.x); o.y = f2bf(v.y); o.z = f2bf(v.z); o.w = f2bf(v.w);
            *(us4*)(xw + i * 32) = o;
        }
    }
    __syncthreads();

    // --- q-GEMM: 32 tok x 96 cols per wave (heads 2w, 2w+1), K=384 ---
    f32x4 acc[2][6];
#pragma unroll
    for (int mt = 0; mt < 2; ++mt)
#pragma unroll
        for (int j = 0; j < 6; ++j) acc[mt][j] = (f32x4){0.f, 0.f, 0.f, 0.f};

#pragma unroll
    for (int ks = 0; ks < 12; ++ks) {
        short8 a0 = *(const short8*)(xs + (c16) * 392 + ks * 32 + q * 8);
        short8 a1 = *(const short8*)(xs + (16 + c16) * 392 + ks * 32 + q * 8);
#pragma unroll
        for (int j = 0; j < 6; ++j) {
            const int nt = w * 6 + j;
            short8 bf = *(const short8*)(WqkvT + (size_t)(nt * 16 + c16) * 384 + ks * 32 + q * 8);
            acc[0][j] = MFMA(a0, bf, acc[0][j]);
            acc[1][j] = MFMA(a1, bf, acc[1][j]);
        }
    }
    __syncthreads();    // xs free for reuse as ys

    // --- softmax over C=48 per (token, head), fully in registers + shfl ---
#pragma unroll
    for (int hh = 0; hh < 2; ++hh) {
        const int h = 2 * w + hh;
        f32x4 e[2][3];
#pragma unroll
        for (int mt = 0; mt < 2; ++mt)
#pragma unroll
            for (int jj = 0; jj < 3; ++jj) {
                f32x4 vv = acc[mt][hh * 3 + jj];
                e[mt][jj].x = __expf(vv.x); e[mt][jj].y = __expf(vv.y);
                e[mt][jj].z = __expf(vv.z); e[mt][jj].w = __expf(vv.w);
            }
#pragma unroll
        for (int mt = 0; mt < 2; ++mt)
#pragma unroll
            for (int r = 0; r < 4; ++r) {
                float ss = e[mt][0][r] + e[mt][1][r] + e[mt][2][r];
                ss += __shfl_xor(ss, 1); ss += __shfl_xor(ss, 2);
                ss += __shfl_xor(ss, 4); ss += __shfl_xor(ss, 8);
                const float inv = 1.0f / ss;
                e[mt][0][r] *= inv; e[mt][1][r] *= inv; e[mt][2][r] *= inv;
            }
        // write q̂ (A-layout, column writes)
#pragma unroll
        for (int mt = 0; mt < 2; ++mt)
#pragma unroll
            for (int jj = 0; jj < 3; ++jj) {
                const int c = jj * 16 + c16;
#pragma unroll
                for (int r = 0; r < 4; ++r) {
                    const int t = mt * 16 + q * 4 + r;
                    qs[t * 520 + h * 64 + c] = f2bf(e[mt][jj][r]);
                }
            }
    }
    {   // zero the K-pad region c in [48,64) for this wave's heads
        const int t = l & 31, hp = l >> 5;
        const int h = 2 * w + hp;
        us8 z8 = {0, 0, 0, 0, 0, 0, 0, 0};
        *(us8*)(qs + t * 520 + h * 64 + 48) = z8;
    }
    __syncthreads();

    // --- y = q̂ @ ctx̂ per head (K=64 padded), write y bf16 into xs as [t][384] ---
#pragma unroll
    for (int hh = 0; hh < 2; ++hh) {
        const int h = 2 * w + hh;
        f32x4 y[2][3];
#pragma unroll
        for (int mt = 0; mt < 2; ++mt)
#pragma unroll
            for (int dt = 0; dt < 3; ++dt) y[mt][dt] = (f32x4){0.f, 0.f, 0.f, 0.f};
#pragma unroll
        for (int ks = 0; ks < 2; ++ks) {
            short8 a0 = *(const short8*)(qs + (c16) * 520 + h * 64 + ks * 32 + q * 8);
            short8 a1 = *(const short8*)(qs + (16 + c16) * 520 + h * 64 + ks * 32 + q * 8);
#pragma unroll
            for (int dt = 0; dt < 3; ++dt) {
                short8 bf = *(const short8*)(ctxT + ((size_t)(b * 8 + h) * 48 + dt * 16 + c16) * 64 + ks * 32 + q * 8);
                y[0][dt] = MFMA(a0, bf, y[0][dt]);
                y[1][dt] = MFMA(a1, bf, y[1][dt]);
            }
        }
#pragma unroll
        for (int mt = 0; mt < 2; ++mt)
#pragma unroll
            for (int dt = 0; dt < 3; ++dt) {
                const int dcol = h * 48 + dt * 16 + c16;
#pragma unroll
                for (int r = 0; r < 4; ++r) {
                    const int t = mt * 16 + q * 4 + r;
                    xs[t * 392 + dcol] = f2bf(y[mt][dt][r]);
                }
            }
    }
    __syncthreads();

    // --- proj: out = y @ Wp + b, 32 tok x 96 cols per wave, K=384 ---
    f32x4 po[2][6];
#pragma unroll
    for (int mt = 0; mt < 2; ++mt)
#pragma unroll
        for (int j = 0; j < 6; ++j) po[mt][j] = (f32x4){0.f, 0.f, 0.f, 0.f};

#pragma unroll
    for (int ks = 0; ks < 12; ++ks) {
        short8 a0 = *(const short8*)(xs + (c16) * 392 + ks * 32 + q * 8);
        short8 a1 = *(const short8*)(xs + (16 + c16) * 392 + ks * 32 + q * 8);
#pragma unroll
        for (int j = 0; j < 6; ++j) {
            const int nt = w * 6 + j;
            short8 bf = *(const short8*)(WpT + (size_t)(nt * 16 + c16) * 384 + ks * 32 + q * 8);
            po[0][j] = MFMA(a0, bf, po[0][j]);
            po[1][j] = MFMA(a1, bf, po[1][j]);
        }
    }

    // --- epilogue: bias + non-temporal store (out is write-once) ---
#pragma unroll
    for (int j = 0; j < 6; ++j) {
        const int col = (w * 6 + j) * 16 + c16;
        const float bv = bp[col];
#pragma unroll
        for (int mt = 0; mt < 2; ++mt)
#pragma unroll
            for (int r = 0; r < 4; ++r) {
                const int t = mt * 16 + q * 4 + r;
                __builtin_nontemporal_store(po[mt][j][r] + bv,
                                            &out[(tok0 + t) * 384 + col]);
            }
    }
}

// ---------------------------------------------------------------------------
extern "C" void kernel_launch(void* const* d_in, const int* in_sizes, int n_in,
                              void* d_out, int out_size, void* d_ws, size_t ws_size,
                              hipStream_t stream)
{
    (void)in_sizes; (void)n_in; (void)out_size; (void)ws_size;
    const float* x    = (const float*)d_in[0];
    const float* Wqkv = (const float*)d_in[1];
    const float* Wp   = (const float*)d_in[2];
    const float* bp   = (const float*)d_in[3];
    float* out = (float*)d_out;

    char* p = (char*)d_ws;
    float* ctxP = (float*)p;                     p += (size_t)CTXP_ELEMS * 4;  // 18.87 MB
    float* ZP   = (float*)p;                     p += (size_t)ZP_ELEMS * 4;    // 393 KB
    unsigned short* WqkvT = (unsigned short*)p;  p += (size_t)TD_ * D_ * 2;    // 884736 B
    unsigned short* WpT   = (unsigned short*)p;  p += (size_t)D_ * D_ * 2;     // 294912 B
    unsigned short* ctxT  = (unsigned short*)p;                                // 393216 B

    kP<<<dim3(576), dim3(256), 0, stream>>>(Wqkv, Wp, WqkvT, WpT);
    kA<<<dim3(256), dim3(512), 0, stream>>>(x, WqkvT, ctxP, ZP);
    kB<<<dim3(768), dim3(256), 0, stream>>>(ctxP, ZP, ctxT);
    kC<<<dim3(4096), dim3(256), 0, stream>>>(x, WqkvT, ctxT, WpT, bp, out);
}